// Round 1
// baseline (450.508 us; speedup 1.0000x reference)
//
#include <hip/hip_runtime.h>
#include <cstdint>

#define NEG_SLOPE 0.2f

__device__ __forceinline__ float leaky(float v) { return v > 0.f ? v : NEG_SLOPE * v; }

// ---------------- CSR build (dst-sorted adjacency) ----------------

__global__ void count_kernel(const int* __restrict__ dst, int* __restrict__ cnt, int E) {
    int i = blockIdx.x * blockDim.x + threadIdx.x;
    if (i < E) atomicAdd(&cnt[dst[i]], 1);
}

__global__ __launch_bounds__(1024) void scan_kernel(const int* __restrict__ cnt,
                                                    int* __restrict__ rp, int n) {
    __shared__ int part[1024];
    int tid = threadIdx.x;
    int chunk = (n + 1023) >> 10;
    int beg = tid * chunk;
    int end = min(beg + chunk, n);
    int s = 0;
    for (int i = beg; i < end; ++i) s += cnt[i];
    part[tid] = s;
    __syncthreads();
    // Hillis-Steele inclusive scan over 1024 partials
    for (int off = 1; off < 1024; off <<= 1) {
        int v = (tid >= off) ? part[tid - off] : 0;
        __syncthreads();
        part[tid] += v;
        __syncthreads();
    }
    int prefix = (tid == 0) ? 0 : part[tid - 1];
    for (int i = beg; i < end; ++i) { rp[i] = prefix; prefix += cnt[i]; }
    if (tid == 1023) rp[n] = part[1023];
}

__global__ void scatter_kernel(const int* __restrict__ src, const int* __restrict__ dst,
                               const int* __restrict__ rp, int* __restrict__ cnt,
                               int* __restrict__ col, int E) {
    int i = blockIdx.x * blockDim.x + threadIdx.x;
    if (i < E) {
        int d = dst[i];
        int pos = atomicAdd(&cnt[d], 1);
        col[rp[d] + pos] = src[i];
    }
}

// ---------------- GEMM1: h1 = x @ W1  (N x 128) @ (128 x 128) ----------------
// Block tile: 32 rows x 128 cols; 128 threads; thread tile 8 rows x 4 cols.
// W staged in LDS in two 64-k phases to stay <= 48KB LDS.

__global__ __launch_bounds__(128) void gemm1_kernel(const float* __restrict__ x,
                                                    const float* __restrict__ W,
                                                    float* __restrict__ h1, int n) {
    __shared__ float Wl[64 * 128];   // 32KB
    __shared__ float xl[32][128];    // 16KB
    int tid = threadIdx.x;
    int row0 = blockIdx.x * 32;
    for (int r = 0; r < 32; ++r) {
        int row = row0 + r;
        xl[r][tid] = (row < n) ? x[(size_t)row * 128 + tid] : 0.f;
    }
    int t = tid & 31, g = tid >> 5;
    int c0 = t * 4, r0 = g * 8;
    float acc[8][4];
#pragma unroll
    for (int r = 0; r < 8; ++r) { acc[r][0] = acc[r][1] = acc[r][2] = acc[r][3] = 0.f; }

    const float4* W4 = (const float4*)W;
    float4* Wl4 = (float4*)Wl;
    for (int kb = 0; kb < 2; ++kb) {
        __syncthreads();
#pragma unroll
        for (int i = 0; i < 16; ++i) Wl4[tid + i * 128] = W4[kb * 2048 + tid + i * 128];
        __syncthreads();
        for (int k = 0; k < 64; ++k) {
            float4 w = *(const float4*)&Wl[k * 128 + c0];
#pragma unroll
            for (int r = 0; r < 8; ++r) {
                float xv = xl[r0 + r][kb * 64 + k];
                acc[r][0] += xv * w.x; acc[r][1] += xv * w.y;
                acc[r][2] += xv * w.z; acc[r][3] += xv * w.w;
            }
        }
    }
#pragma unroll
    for (int r = 0; r < 8; ++r) {
        int row = row0 + r0 + r;
        if (row < n) {
            *(float4*)&h1[(size_t)row * 128 + c0] =
                make_float4(acc[r][0], acc[r][1], acc[r][2], acc[r][3]);
        }
    }
}

// ---------------- GEMM2: h2 = hp @ W2  (N x 128) @ (128 x 32) ----------------
// Block tile: 32 rows x 32 cols; 256 threads; thread tile 1 row x 4 cols.

__global__ __launch_bounds__(256) void gemm2_kernel(const float* __restrict__ hp,
                                                    const float* __restrict__ W2,
                                                    float* __restrict__ h2, int n) {
    __shared__ float Wl[128 * 32];   // 16KB
    __shared__ float xl[32][129];    // padded: breaks 8-way bank conflict on xl[r][k]
    int tid = threadIdx.x;
    const float4* W4 = (const float4*)W2;
    float4* Wl4 = (float4*)Wl;
#pragma unroll
    for (int i = 0; i < 4; ++i) Wl4[tid + i * 256] = W4[tid + i * 256];
    int row0 = blockIdx.x * 32;
    for (int f = tid; f < 32 * 128; f += 256) {
        int r = f >> 7, k = f & 127;
        int row = row0 + r;
        xl[r][k] = (row < n) ? hp[(size_t)row * 128 + k] : 0.f;
    }
    __syncthreads();
    int cg = tid & 7, r = tid >> 3;
    int c0 = cg * 4;
    float a0 = 0, a1 = 0, a2 = 0, a3 = 0;
    for (int k = 0; k < 128; ++k) {
        float4 w = *(const float4*)&Wl[k * 32 + c0];
        float xv = xl[r][k];
        a0 += xv * w.x; a1 += xv * w.y; a2 += xv * w.z; a3 += xv * w.w;
    }
    int row = row0 + r;
    if (row < n) *(float4*)&h2[(size_t)row * 32 + c0] = make_float4(a0, a1, a2, a3);
}

// ---------------- alpha dots ----------------

__global__ __launch_bounds__(256) void alpha1_kernel(const float* __restrict__ h1,
                                                     const float* __restrict__ a_src,
                                                     const float* __restrict__ a_dst,
                                                     float* __restrict__ as, float* __restrict__ ad,
                                                     int n) {
    int tid = threadIdx.x;
    int row = blockIdx.x * 2 + (tid >> 7);
    int c = tid & 127;
    if (row >= n) return;
    float v = h1[(size_t)row * 128 + c];
    float ps = v * a_src[c];   // a_src is (4,32) flat == 128, matches c
    float pd = v * a_dst[c];
#pragma unroll
    for (int o = 16; o > 0; o >>= 1) {
        ps += __shfl_xor(ps, o);
        pd += __shfl_xor(pd, o);
    }
    if ((c & 31) == 0) {
        int head = c >> 5;
        as[row * 4 + head] = ps;
        ad[row * 4 + head] = pd;
    }
}

__global__ __launch_bounds__(256) void alpha2_kernel(const float* __restrict__ h2,
                                                     const float* __restrict__ a_src,
                                                     const float* __restrict__ a_dst,
                                                     float* __restrict__ as, float* __restrict__ ad,
                                                     int n) {
    int tid = threadIdx.x;
    int row = blockIdx.x * 8 + (tid >> 5);
    int c = tid & 31;
    if (row >= n) return;
    float v = h2[(size_t)row * 32 + c];
    float ps = v * a_src[c];
    float pd = v * a_dst[c];
#pragma unroll
    for (int o = 16; o > 0; o >>= 1) {
        ps += __shfl_xor(ps, o);
        pd += __shfl_xor(pd, o);
    }
    if (c == 0) { as[row] = ps; ad[row] = pd; }
}

// ---------------- layer-1 softmax + aggregate (4 heads x 32 ch) ----------------
// One block (128 threads) per dst node; thread owns one output channel.
// Two passes: (1) segment max, (2) exp + weighted gather-accumulate; self-loop fused.
// Epilogue: + b1, ELU, write hp.

__global__ __launch_bounds__(128) void agg1_kernel(const float* __restrict__ h1,
                                                   const float4* __restrict__ as1,
                                                   const float4* __restrict__ ad1,
                                                   const int* __restrict__ rp,
                                                   const int* __restrict__ col,
                                                   const float* __restrict__ b1,
                                                   float* __restrict__ hp, int n) {
    int nid = blockIdx.x;
    int tid = threadIdx.x;
    int start = rp[nid], end = rp[nid + 1];
    float4 adn = ad1[nid];
    float4 asn = as1[nid];
    float e0 = leaky(asn.x + adn.x), e1 = leaky(asn.y + adn.y),
          e2 = leaky(asn.z + adn.z), e3 = leaky(asn.w + adn.w);
    float m0 = e0, m1 = e1, m2 = e2, m3 = e3;
    for (int i = start + tid; i < end; i += 128) {
        float4 a = as1[col[i]];
        m0 = fmaxf(m0, leaky(a.x + adn.x));
        m1 = fmaxf(m1, leaky(a.y + adn.y));
        m2 = fmaxf(m2, leaky(a.z + adn.z));
        m3 = fmaxf(m3, leaky(a.w + adn.w));
    }
    __shared__ float4 red[128];
    red[tid] = make_float4(m0, m1, m2, m3);
    __syncthreads();
    for (int s = 64; s > 0; s >>= 1) {
        if (tid < s) {
            float4 a = red[tid], b = red[tid + s];
            red[tid] = make_float4(fmaxf(a.x, b.x), fmaxf(a.y, b.y),
                                   fmaxf(a.z, b.z), fmaxf(a.w, b.w));
        }
        __syncthreads();
    }
    float4 M = red[0];
    __syncthreads();

    __shared__ int s_src[128];
    __shared__ float s_p[128 * 4];
    float acc = 0.f;
    float d0 = 0.f, d1 = 0.f, d2 = 0.f, d3 = 0.f;
    int head = tid >> 5;
    for (int base = start; base < end; base += 128) {
        int i = base + tid;
        if (i < end) {
            int sidx = col[i];
            float4 a = as1[sidx];
            float p0 = __expf(leaky(a.x + adn.x) - M.x);
            float p1 = __expf(leaky(a.y + adn.y) - M.y);
            float p2 = __expf(leaky(a.z + adn.z) - M.z);
            float p3 = __expf(leaky(a.w + adn.w) - M.w);
            s_src[tid] = sidx;
            s_p[tid * 4 + 0] = p0; s_p[tid * 4 + 1] = p1;
            s_p[tid * 4 + 2] = p2; s_p[tid * 4 + 3] = p3;
            d0 += p0; d1 += p1; d2 += p2; d3 += p3;
        }
        __syncthreads();
        int len = min(128, end - base);
        for (int j = 0; j < len; ++j) {
            acc += s_p[j * 4 + head] * h1[(size_t)s_src[j] * 128 + tid];
        }
        __syncthreads();
    }
    float ps0 = __expf(e0 - M.x), ps1 = __expf(e1 - M.y),
          ps2 = __expf(e2 - M.z), ps3 = __expf(e3 - M.w);
    float psh = (head == 0) ? ps0 : (head == 1) ? ps1 : (head == 2) ? ps2 : ps3;
    acc += psh * h1[(size_t)nid * 128 + tid];

    red[tid] = make_float4(d0, d1, d2, d3);
    __syncthreads();
    for (int s = 64; s > 0; s >>= 1) {
        if (tid < s) {
            float4 a = red[tid], b = red[tid + s];
            red[tid] = make_float4(a.x + b.x, a.y + b.y, a.z + b.z, a.w + b.w);
        }
        __syncthreads();
    }
    float4 D = red[0];
    float denom = (head == 0) ? D.x + ps0 : (head == 1) ? D.y + ps1
                : (head == 2) ? D.z + ps2 : D.w + ps3;
    float outv = acc / denom + b1[tid];
    outv = outv > 0.f ? outv : expm1f(outv);   // ELU
    hp[(size_t)nid * 128 + tid] = outv;
}

// ---------------- layer-2 softmax + aggregate (1 head x 32 ch) ----------------
// One wave per dst node; lanes 0-31 / 32-63 split edges, channel = lane & 31.

__global__ __launch_bounds__(64) void agg2_kernel(const float* __restrict__ h2,
                                                  const float* __restrict__ as2,
                                                  const float* __restrict__ ad2,
                                                  const int* __restrict__ rp,
                                                  const int* __restrict__ col,
                                                  const float* __restrict__ b2,
                                                  float* __restrict__ out, int n) {
    int nid = blockIdx.x;
    int lane = threadIdx.x;
    int start = rp[nid], end = rp[nid + 1];
    float adn = ad2[nid];
    float e_self = leaky(as2[nid] + adn);
    float m = e_self;
    for (int i = start + lane; i < end; i += 64)
        m = fmaxf(m, leaky(as2[col[i]] + adn));
#pragma unroll
    for (int o = 32; o > 0; o >>= 1) m = fmaxf(m, __shfl_xor(m, o));

    __shared__ int s_src[64];
    __shared__ float s_p[64];
    float acc = 0.f, dsum = 0.f;
    int ch = lane & 31, sub = lane >> 5;
    for (int base = start; base < end; base += 64) {
        int i = base + lane;
        if (i < end) {
            int sidx = col[i];
            float p = __expf(leaky(as2[sidx] + adn) - m);
            s_src[lane] = sidx;
            s_p[lane] = p;
            dsum += p;
        }
        __syncthreads();
        int len = min(64, end - base);
        for (int j = sub; j < len; j += 2)
            acc += s_p[j] * h2[(size_t)s_src[j] * 32 + ch];
        __syncthreads();
    }
    float p_self = __expf(e_self - m);
    if (sub == 0) acc += p_self * h2[(size_t)nid * 32 + ch];
    if (lane == 0) dsum += p_self;
#pragma unroll
    for (int o = 32; o > 0; o >>= 1) dsum += __shfl_xor(dsum, o);
    acc += __shfl_down(acc, 32);
    if (lane < 32) out[(size_t)nid * 32 + ch] = acc / dsum + b2[ch];
}

// ---------------- launch ----------------

extern "C" void kernel_launch(void* const* d_in, const int* in_sizes, int n_in,
                              void* d_out, int out_size, void* d_ws, size_t ws_size,
                              hipStream_t stream) {
    const float* x      = (const float*)d_in[0];
    const int*   ei     = (const int*)d_in[1];
    const float* W1     = (const float*)d_in[2];
    const float* a_src1 = (const float*)d_in[3];
    const float* a_dst1 = (const float*)d_in[4];
    const float* b1     = (const float*)d_in[5];
    const float* W2     = (const float*)d_in[6];
    const float* a_src2 = (const float*)d_in[7];
    const float* a_dst2 = (const float*)d_in[8];
    const float* b2     = (const float*)d_in[9];
    float* out = (float*)d_out;

    const int N = in_sizes[0] / 128;
    const int E = in_sizes[1] / 2;
    const int* src = ei;
    const int* dstp = ei + E;

    uint8_t* w = (uint8_t*)d_ws;
    auto carve = [&](size_t bytes) {
        uint8_t* p = w;
        w += (bytes + 255) & ~(size_t)255;
        return p;
    };
    float* h1  = (float*)carve((size_t)N * 128 * 4);
    float* hp  = (float*)carve((size_t)N * 128 * 4);
    float* h2  = (float*)carve((size_t)N * 32 * 4);
    float* as1 = (float*)carve((size_t)N * 4 * 4);
    float* ad1 = (float*)carve((size_t)N * 4 * 4);
    float* as2 = (float*)carve((size_t)N * 4);
    float* ad2 = (float*)carve((size_t)N * 4);
    int* rp  = (int*)carve((size_t)(N + 1) * 4);
    int* cnt = (int*)carve((size_t)N * 4);
    int* col = (int*)carve((size_t)E * 4);

    // CSR build
    hipMemsetAsync(cnt, 0, (size_t)N * 4, stream);
    count_kernel<<<(E + 255) / 256, 256, 0, stream>>>(dstp, cnt, E);
    scan_kernel<<<1, 1024, 0, stream>>>(cnt, rp, N);
    hipMemsetAsync(cnt, 0, (size_t)N * 4, stream);
    scatter_kernel<<<(E + 255) / 256, 256, 0, stream>>>(src, dstp, rp, cnt, col, E);

    // layer 1
    gemm1_kernel<<<(N + 31) / 32, 128, 0, stream>>>(x, W1, h1, N);
    alpha1_kernel<<<(N + 1) / 2, 256, 0, stream>>>(h1, a_src1, a_dst1, as1, ad1, N);
    agg1_kernel<<<N, 128, 0, stream>>>(h1, (const float4*)as1, (const float4*)ad1,
                                       rp, col, b1, hp, N);
    // layer 2
    gemm2_kernel<<<(N + 31) / 32, 256, 0, stream>>>(hp, W2, h2, N);
    alpha2_kernel<<<(N + 7) / 8, 256, 0, stream>>>(h2, a_src2, a_dst2, as2, ad2, N);
    agg2_kernel<<<N, 64, 0, stream>>>(h2, as2, ad2, rp, col, b2, out, N);
}

// Round 4
// 375.556 us; speedup vs baseline: 1.1996x; 1.1996x over previous
//
#include <hip/hip_runtime.h>
#include <cstdint>

#define NEG_SLOPE 0.2f

__device__ __forceinline__ float leaky(float v) { return v > 0.f ? v : NEG_SLOPE * v; }

// ---------------- CSR build (dst-sorted adjacency) ----------------

__global__ void count_kernel(const int* __restrict__ dst, int* __restrict__ cnt, int E) {
    int i = blockIdx.x * blockDim.x + threadIdx.x;
    if (i < E) atomicAdd(&cnt[dst[i]], 1);
}

// scanA: per-block (1024 elems) sums
__global__ __launch_bounds__(256) void scanA_kernel(const int* __restrict__ cnt,
                                                    int* __restrict__ bsum, int n) {
    int base = blockIdx.x * 1024 + threadIdx.x * 4;
    int s = 0;
    if (base + 3 < n) {
        int4 v = *(const int4*)(cnt + base);
        s = v.x + v.y + v.z + v.w;
    } else {
        for (int j = 0; j < 4; ++j) if (base + j < n) s += cnt[base + j];
    }
#pragma unroll
    for (int o = 1; o < 64; o <<= 1) s += __shfl_xor(s, o);
    __shared__ int ws_[4];
    if ((threadIdx.x & 63) == 0) ws_[threadIdx.x >> 6] = s;
    __syncthreads();
    if (threadIdx.x == 0) bsum[blockIdx.x] = ws_[0] + ws_[1] + ws_[2] + ws_[3];
}

// scanB: inclusive scan of block sums (G <= 1024)
__global__ __launch_bounds__(1024) void scanB_kernel(int* __restrict__ bsum, int G) {
    __shared__ int sm[1024];
    int t = threadIdx.x;
    sm[t] = (t < G) ? bsum[t] : 0;
    __syncthreads();
    for (int o = 1; o < 1024; o <<= 1) {
        int u = (t >= o) ? sm[t - o] : 0;
        __syncthreads();
        sm[t] += u;
        __syncthreads();
    }
    if (t < G) bsum[t] = sm[t];
}

// scanC: final exclusive scan -> rp (rp[n] = total)
__global__ __launch_bounds__(256) void scanC_kernel(const int* __restrict__ cnt,
                                                    const int* __restrict__ bscan,
                                                    int* __restrict__ rp, int n) {
    int b = blockIdx.x, t = threadIdx.x;
    int base = b * 1024 + t * 4;
    int v[4]; int s = 0;
#pragma unroll
    for (int j = 0; j < 4; ++j) { int idx = base + j; v[j] = (idx < n) ? cnt[idx] : 0; s += v[j]; }
    int lane = t & 63;
    int x = s;
#pragma unroll
    for (int o = 1; o < 64; o <<= 1) { int u = __shfl_up(x, o); if (lane >= o) x += u; }
    __shared__ int wsum[4], woff[4];
    if (lane == 63) wsum[t >> 6] = x;
    __syncthreads();
    if (t == 0) { int a = 0; for (int i = 0; i < 4; ++i) { woff[i] = a; a += wsum[i]; } }
    __syncthreads();
    int off = ((b == 0) ? 0 : bscan[b - 1]) + (x - s) + woff[t >> 6];
#pragma unroll
    for (int j = 0; j < 4; ++j) {
        int idx = base + j;
        if (idx <= n) rp[idx] = off;
        off += v[j];
    }
}

__global__ void scatter_kernel(const int* __restrict__ src, const int* __restrict__ dst,
                               const int* __restrict__ rp, int* __restrict__ cnt,
                               int* __restrict__ col, int E) {
    int i = blockIdx.x * blockDim.x + threadIdx.x;
    if (i < E) {
        int d = dst[i];
        int pos = atomicAdd(&cnt[d], 1);
        col[rp[d] + pos] = src[i];
    }
}

// ---------------- GEMM1: h1 = x @ W1  (64x128 tile) ----------------

__global__ __launch_bounds__(128) void gemm1_kernel(const float* __restrict__ x,
                                                    const float* __restrict__ W,
                                                    float* __restrict__ h1, int n) {
    __shared__ float xl[64][129];
    __shared__ float Wl[64 * 128];
    int tid = threadIdx.x;
    int row0 = blockIdx.x * 64;
    for (int i = 0; i < 16; ++i) {
        int idx = tid + i * 128;            // float4 index over 64x32
        int r = idx >> 5, c4 = idx & 31;
        float4 v = make_float4(0.f, 0.f, 0.f, 0.f);
        if (row0 + r < n) v = *(const float4*)(x + (size_t)(row0 + r) * 128 + c4 * 4);
        xl[r][c4 * 4 + 0] = v.x; xl[r][c4 * 4 + 1] = v.y;
        xl[r][c4 * 4 + 2] = v.z; xl[r][c4 * 4 + 3] = v.w;
    }
    int r0 = (tid >> 4) * 8, c0 = (tid & 15) * 4;
    float4 acc[8][2];
#pragma unroll
    for (int r = 0; r < 8; ++r) {
        acc[r][0] = make_float4(0.f, 0.f, 0.f, 0.f);
        acc[r][1] = make_float4(0.f, 0.f, 0.f, 0.f);
    }
    const float4* W4 = (const float4*)W;
    float4* Wl4 = (float4*)Wl;
    for (int kb = 0; kb < 2; ++kb) {
        __syncthreads();
#pragma unroll
        for (int i = 0; i < 16; ++i) Wl4[tid + i * 128] = W4[kb * 2048 + tid + i * 128];
        __syncthreads();
        for (int k = 0; k < 64; ++k) {
            float4 w0 = *(float4*)&Wl[k * 128 + c0];
            float4 w1 = *(float4*)&Wl[k * 128 + c0 + 64];
            int kk = kb * 64 + k;
#pragma unroll
            for (int r = 0; r < 8; ++r) {
                float xv = xl[r0 + r][kk];
                acc[r][0].x += xv * w0.x; acc[r][0].y += xv * w0.y;
                acc[r][0].z += xv * w0.z; acc[r][0].w += xv * w0.w;
                acc[r][1].x += xv * w1.x; acc[r][1].y += xv * w1.y;
                acc[r][1].z += xv * w1.z; acc[r][1].w += xv * w1.w;
            }
        }
    }
#pragma unroll
    for (int r = 0; r < 8; ++r) {
        int row = row0 + r0 + r;
        if (row < n) {
            *(float4*)&h1[(size_t)row * 128 + c0] = acc[r][0];
            *(float4*)&h1[(size_t)row * 128 + c0 + 64] = acc[r][1];
        }
    }
}

// ---------------- GEMM2: h2 = hp @ W2 (round-1 core, proven) ----------------

__global__ __launch_bounds__(256) void gemm2_kernel(const float* __restrict__ hp,
                                                    const float* __restrict__ W2,
                                                    float* __restrict__ h2, int n) {
    __shared__ float Wl[128 * 32];
    __shared__ float xl[32][129];
    int tid = threadIdx.x;
    const float4* W4 = (const float4*)W2;
    float4* Wl4 = (float4*)Wl;
#pragma unroll
    for (int i = 0; i < 4; ++i) Wl4[tid + i * 256] = W4[tid + i * 256];
    int row0 = blockIdx.x * 32;
    for (int f = tid; f < 32 * 128; f += 256) {
        int r = f >> 7, k = f & 127;
        int row = row0 + r;
        xl[r][k] = (row < n) ? hp[(size_t)row * 128 + k] : 0.f;
    }
    __syncthreads();
    int cg = tid & 7, r = tid >> 3;
    int c0 = cg * 4;
    float a0 = 0, a1 = 0, a2 = 0, a3 = 0;
    for (int k = 0; k < 128; ++k) {
        float4 w = *(const float4*)&Wl[k * 32 + c0];
        float xv = xl[r][k];
        a0 += xv * w.x; a1 += xv * w.y; a2 += xv * w.z; a3 += xv * w.w;
    }
    int row = row0 + r;
    if (row < n) *(float4*)&h2[(size_t)row * 32 + c0] = make_float4(a0, a1, a2, a3);
}

// ---------------- alpha dots (round-1 versions, proven) ----------------

__global__ __launch_bounds__(256) void alpha1_kernel(const float* __restrict__ h1,
                                                     const float* __restrict__ a_src,
                                                     const float* __restrict__ a_dst,
                                                     float* __restrict__ as, float* __restrict__ ad,
                                                     int n) {
    int tid = threadIdx.x;
    int row = blockIdx.x * 2 + (tid >> 7);
    int c = tid & 127;
    if (row >= n) return;
    float v = h1[(size_t)row * 128 + c];
    float ps = v * a_src[c];
    float pd = v * a_dst[c];
#pragma unroll
    for (int o = 16; o > 0; o >>= 1) {
        ps += __shfl_xor(ps, o);
        pd += __shfl_xor(pd, o);
    }
    if ((c & 31) == 0) {
        int head = c >> 5;
        as[row * 4 + head] = ps;
        ad[row * 4 + head] = pd;
    }
}

__global__ __launch_bounds__(256) void alpha2_kernel(const float* __restrict__ h2,
                                                     const float* __restrict__ a_src,
                                                     const float* __restrict__ a_dst,
                                                     float* __restrict__ as, float* __restrict__ ad,
                                                     int n) {
    int tid = threadIdx.x;
    int row = blockIdx.x * 8 + (tid >> 5);
    int c = tid & 31;
    if (row >= n) return;
    float v = h2[(size_t)row * 32 + c];
    float ps = v * a_src[c];
    float pd = v * a_dst[c];
#pragma unroll
    for (int o = 16; o > 0; o >>= 1) {
        ps += __shfl_xor(ps, o);
        pd += __shfl_xor(pd, o);
    }
    if (c == 0) { as[row] = ps; ad[row] = pd; }
}

// ---------------- layer-1 softmax + aggregate (ROUND-1 VERBATIM, proven) ----------------

__global__ __launch_bounds__(128) void agg1_kernel(const float* __restrict__ h1,
                                                   const float4* __restrict__ as1,
                                                   const float4* __restrict__ ad1,
                                                   const int* __restrict__ rp,
                                                   const int* __restrict__ col,
                                                   const float* __restrict__ b1,
                                                   float* __restrict__ hp, int n) {
    int nid = blockIdx.x;
    int tid = threadIdx.x;
    int start = rp[nid], end = rp[nid + 1];
    float4 adn = ad1[nid];
    float4 asn = as1[nid];
    float e0 = leaky(asn.x + adn.x), e1 = leaky(asn.y + adn.y),
          e2 = leaky(asn.z + adn.z), e3 = leaky(asn.w + adn.w);
    float m0 = e0, m1 = e1, m2 = e2, m3 = e3;
    for (int i = start + tid; i < end; i += 128) {
        float4 a = as1[col[i]];
        m0 = fmaxf(m0, leaky(a.x + adn.x));
        m1 = fmaxf(m1, leaky(a.y + adn.y));
        m2 = fmaxf(m2, leaky(a.z + adn.z));
        m3 = fmaxf(m3, leaky(a.w + adn.w));
    }
    __shared__ float4 red[128];
    red[tid] = make_float4(m0, m1, m2, m3);
    __syncthreads();
    for (int s = 64; s > 0; s >>= 1) {
        if (tid < s) {
            float4 a = red[tid], b = red[tid + s];
            red[tid] = make_float4(fmaxf(a.x, b.x), fmaxf(a.y, b.y),
                                   fmaxf(a.z, b.z), fmaxf(a.w, b.w));
        }
        __syncthreads();
    }
    float4 M = red[0];
    __syncthreads();

    __shared__ int s_src[128];
    __shared__ float s_p[128 * 4];
    float acc = 0.f;
    float d0 = 0.f, d1 = 0.f, d2 = 0.f, d3 = 0.f;
    int head = tid >> 5;
    for (int base = start; base < end; base += 128) {
        int i = base + tid;
        if (i < end) {
            int sidx = col[i];
            float4 a = as1[sidx];
            float p0 = __expf(leaky(a.x + adn.x) - M.x);
            float p1 = __expf(leaky(a.y + adn.y) - M.y);
            float p2 = __expf(leaky(a.z + adn.z) - M.z);
            float p3 = __expf(leaky(a.w + adn.w) - M.w);
            s_src[tid] = sidx;
            s_p[tid * 4 + 0] = p0; s_p[tid * 4 + 1] = p1;
            s_p[tid * 4 + 2] = p2; s_p[tid * 4 + 3] = p3;
            d0 += p0; d1 += p1; d2 += p2; d3 += p3;
        }
        __syncthreads();
        int len = min(128, end - base);
        for (int j = 0; j < len; ++j) {
            acc += s_p[j * 4 + head] * h1[(size_t)s_src[j] * 128 + tid];
        }
        __syncthreads();
    }
    float ps0 = __expf(e0 - M.x), ps1 = __expf(e1 - M.y),
          ps2 = __expf(e2 - M.z), ps3 = __expf(e3 - M.w);
    float psh = (head == 0) ? ps0 : (head == 1) ? ps1 : (head == 2) ? ps2 : ps3;
    acc += psh * h1[(size_t)nid * 128 + tid];

    red[tid] = make_float4(d0, d1, d2, d3);
    __syncthreads();
    for (int s = 64; s > 0; s >>= 1) {
        if (tid < s) {
            float4 a = red[tid], b = red[tid + s];
            red[tid] = make_float4(a.x + b.x, a.y + b.y, a.z + b.z, a.w + b.w);
        }
        __syncthreads();
    }
    float4 D = red[0];
    float denom = (head == 0) ? D.x + ps0 : (head == 1) ? D.y + ps1
                : (head == 2) ? D.z + ps2 : D.w + ps3;
    float outv = acc / denom + b1[tid];
    outv = outv > 0.f ? outv : expm1f(outv);   // ELU
    hp[(size_t)nid * 128 + tid] = outv;
}

// ---------------- layer-2 softmax + aggregate (ROUND-1 VERBATIM, proven) ----------------

__global__ __launch_bounds__(64) void agg2_kernel(const float* __restrict__ h2,
                                                  const float* __restrict__ as2,
                                                  const float* __restrict__ ad2,
                                                  const int* __restrict__ rp,
                                                  const int* __restrict__ col,
                                                  const float* __restrict__ b2,
                                                  float* __restrict__ out, int n) {
    int nid = blockIdx.x;
    int lane = threadIdx.x;
    int start = rp[nid], end = rp[nid + 1];
    float adn = ad2[nid];
    float e_self = leaky(as2[nid] + adn);
    float m = e_self;
    for (int i = start + lane; i < end; i += 64)
        m = fmaxf(m, leaky(as2[col[i]] + adn));
#pragma unroll
    for (int o = 32; o > 0; o >>= 1) m = fmaxf(m, __shfl_xor(m, o));

    __shared__ int s_src[64];
    __shared__ float s_p[64];
    float acc = 0.f, dsum = 0.f;
    int ch = lane & 31, sub = lane >> 5;
    for (int base = start; base < end; base += 64) {
        int i = base + lane;
        if (i < end) {
            int sidx = col[i];
            float p = __expf(leaky(as2[sidx] + adn) - m);
            s_src[lane] = sidx;
            s_p[lane] = p;
            dsum += p;
        }
        __syncthreads();
        int len = min(64, end - base);
        for (int j = sub; j < len; j += 2)
            acc += s_p[j] * h2[(size_t)s_src[j] * 32 + ch];
        __syncthreads();
    }
    float p_self = __expf(e_self - m);
    if (sub == 0) acc += p_self * h2[(size_t)nid * 32 + ch];
    if (lane == 0) dsum += p_self;
#pragma unroll
    for (int o = 32; o > 0; o >>= 1) dsum += __shfl_xor(dsum, o);
    acc += __shfl_down(acc, 32);
    if (lane < 32) out[(size_t)nid * 32 + ch] = acc / dsum + b2[ch];
}

// ---------------- launch ----------------

extern "C" void kernel_launch(void* const* d_in, const int* in_sizes, int n_in,
                              void* d_out, int out_size, void* d_ws, size_t ws_size,
                              hipStream_t stream) {
    const float* x      = (const float*)d_in[0];
    const int*   ei     = (const int*)d_in[1];
    const float* W1     = (const float*)d_in[2];
    const float* a_src1 = (const float*)d_in[3];
    const float* a_dst1 = (const float*)d_in[4];
    const float* b1     = (const float*)d_in[5];
    const float* W2     = (const float*)d_in[6];
    const float* a_src2 = (const float*)d_in[7];
    const float* a_dst2 = (const float*)d_in[8];
    const float* b2     = (const float*)d_in[9];
    float* out = (float*)d_out;

    const int N = in_sizes[0] / 128;
    const int E = in_sizes[1] / 2;
    const int* src = ei;
    const int* dstp = ei + E;

    uint8_t* w = (uint8_t*)d_ws;
    auto carve = [&](size_t bytes) {
        uint8_t* p = w;
        w += (bytes + 255) & ~(size_t)255;
        return p;
    };
    float* h1  = (float*)carve((size_t)N * 128 * 4);
    float* hp  = (float*)carve((size_t)N * 128 * 4);
    float* h2  = (float*)carve((size_t)N * 32 * 4);
    float* as1 = (float*)carve((size_t)N * 4 * 4);
    float* ad1 = (float*)carve((size_t)N * 4 * 4);
    float* as2 = (float*)carve((size_t)N * 4);
    float* ad2 = (float*)carve((size_t)N * 4);
    int* rp   = (int*)carve((size_t)(N + 1) * 4);
    int* cnt  = (int*)carve((size_t)N * 4);
    int* col  = (int*)carve((size_t)E * 4);
    int* bsum = (int*)carve(1024 * 4);

    const int G = (N + 1023) / 1024;   // <= 1024

    // CSR build
    hipMemsetAsync(cnt, 0, (size_t)N * 4, stream);
    count_kernel<<<(E + 255) / 256, 256, 0, stream>>>(dstp, cnt, E);
    scanA_kernel<<<G, 256, 0, stream>>>(cnt, bsum, N);
    scanB_kernel<<<1, 1024, 0, stream>>>(bsum, G);
    scanC_kernel<<<G, 256, 0, stream>>>(cnt, bsum, rp, N);
    hipMemsetAsync(cnt, 0, (size_t)N * 4, stream);
    scatter_kernel<<<(E + 255) / 256, 256, 0, stream>>>(src, dstp, rp, cnt, col, E);

    // layer 1
    gemm1_kernel<<<(N + 63) / 64, 128, 0, stream>>>(x, W1, h1, N);
    alpha1_kernel<<<(N + 1) / 2, 256, 0, stream>>>(h1, a_src1, a_dst1, as1, ad1, N);
    agg1_kernel<<<N, 128, 0, stream>>>(h1, (const float4*)as1, (const float4*)ad1,
                                       rp, col, b1, hp, N);
    // layer 2
    gemm2_kernel<<<(N + 31) / 32, 256, 0, stream>>>(hp, W2, h2, N);
    alpha2_kernel<<<(N + 7) / 8, 256, 0, stream>>>(h2, a_src2, a_dst2, as2, ad2, N);
    agg2_kernel<<<N, 64, 0, stream>>>(h2, as2, ad2, rp, col, b2, out, N);
}